// Round 3
// baseline (40.591 us; speedup 1.0000x reference)
//
#include <hip/hip_runtime.h>
#include <math.h>

#define EPS_T 1e-4f
#define BIG 1e10f
#define NRM_EPS 1e-12f

typedef float v2f __attribute__((ext_vector_type(2)));

// Builds pair-SoA sphere table in d_ws: per pair j (2 spheres):
// {x0,x1, y0,y1, z0,z1, w0,w1}, w = |c|^2 - r^2.  (2 KB for S=128)
__global__ __launch_bounds__(64) void prep_kernel(
    const float* __restrict__ centers, const float* __restrict__ radii,
    float* __restrict__ tb, int SP)
{
    int j = threadIdx.x + blockIdx.x * blockDim.x;
    if (j < SP) {
        float x0 = centers[6 * j + 0], y0 = centers[6 * j + 1], z0 = centers[6 * j + 2];
        float x1 = centers[6 * j + 3], y1 = centers[6 * j + 4], z1 = centers[6 * j + 5];
        float r0 = radii[2 * j + 0],   r1 = radii[2 * j + 1];
        float w0 = x0 * x0 + y0 * y0 + z0 * z0 - r0 * r0;
        float w1 = x1 * x1 + y1 * y1 + z1 * z1 - r1 * r1;
        float* p = tb + 8 * j;
        p[0] = x0; p[1] = x1; p[2] = y0; p[3] = y1;
        p[4] = z0; p[5] = z1; p[6] = w0; p[7] = w1;
    }
}

__global__ __launch_bounds__(256) void illum_kernel(
    const float* __restrict__ ray_o,
    const float* __restrict__ ray_d,
    const float* __restrict__ centers,
    const float* __restrict__ light_pos,
    const int*   __restrict__ light_idx,
    const float* __restrict__ tb,   // pair-SoA table (uniform-indexed -> SGPR loads)
    float* __restrict__ out,        // [N*3] results, then [N] active(0/1)
    int N, int S)
{
    const int i = blockIdx.x * blockDim.x + threadIdx.x;
    if (i >= N) return;

    float ox = ray_o[3 * i + 0], oy = ray_o[3 * i + 1], oz = ray_o[3 * i + 2];
    float dx = ray_d[3 * i + 0], dy = ray_d[3 * i + 1], dz = ray_d[3 * i + 2];

    // d = normalize(ray_d), precise (once per ray)
    float dn  = sqrtf(dx * dx + dy * dy + dz * dz);
    float din = 1.0f / fmaxf(dn, NRM_EPS);
    dx *= din; dy *= din; dz *= din;

    const float od = ox * dx + oy * dy + oz * dz;
    const float oo = ox * ox + oy * oy + oz * oz;

    const int SP = S >> 1;   // 64 pairs

    // 4 independent (tmin, sidx) chains; chain k handles pairs k, k+4, ...
    float tm[4] = {BIG, BIG, BIG, BIG};
    int   id[4] = {0, 2, 4, 6};

    const float4* tb4 = (const float4*)tb;

    for (int j = 0; j < SP; j += 4) {
        #pragma unroll
        for (int k = 0; k < 4; ++k) {
            const int jp = j + k;                 // loop-uniform pair index
            float4 ab = tb4[2 * jp + 0];          // x0,x1,y0,y1  (s_load)
            float4 zw = tb4[2 * jp + 1];          // z0,z1,w0,w1  (s_load)
            v2f cx = {ab.x, ab.y};
            v2f cy = {ab.z, ab.w};
            v2f cz = {zw.x, zw.y};
            v2f cw = {zw.z, zw.w};

            // identical expression forms to the passed round-2 kernel
            v2f doc = dx * cx + dy * cy + dz * cz;
            v2f ooc = ox * cx + oy * cy + oz * cz;
            v2f bm  = doc - od;                    // -b
            v2f cv  = oo - 2.0f * ooc + cw;
            v2f dsc = bm * bm - cv;

            float sq0 = __builtin_amdgcn_sqrtf(dsc.x);
            float sq1 = __builtin_amdgcn_sqrtf(dsc.y);
            float t0  = bm.x - sq0;
            float t1  = bm.y - sq1;

            // sequential within the chain: element 0 before element 1, strict <
            bool c0 = (dsc.x > 0.0f) & (t0 > EPS_T) & (t0 < tm[k]);
            tm[k] = c0 ? t0 : tm[k];
            id[k] = c0 ? (2 * jp + 0) : id[k];
            bool c1 = (dsc.y > 0.0f) & (t1 > EPS_T) & (t1 < tm[k]);
            tm[k] = c1 ? t1 : tm[k];
            id[k] = c1 ? (2 * jp + 1) : id[k];
        }
    }

    // index-aware merge preserves jnp.argmin first-occurrence semantics exactly
    float tA = tm[0]; int iA = id[0];
    { bool b = (tm[1] < tA) | ((tm[1] == tA) & (id[1] < iA)); tA = b ? tm[1] : tA; iA = b ? id[1] : iA; }
    float tB = tm[2]; int iB = id[2];
    { bool b = (tm[3] < tB) | ((tm[3] == tB) & (id[3] < iB)); tB = b ? tm[3] : tB; iB = b ? id[3] : iB; }
    float tmin = tA; int sidx = iA;
    { bool b = (tB < tmin) | ((tB == tmin) & (iB < sidx)); tmin = b ? tB : tmin; sidx = b ? iB : sidx; }

    const bool active = (tmin < BIG);

    // hit point
    float px = fmaf(tmin, dx, ox);
    float py = fmaf(tmin, dy, oy);
    float pz = fmaf(tmin, dz, oz);

    // surface normal (per-lane global fetch, 2 KB table, L2-resident)
    float cbx = centers[3 * sidx + 0];
    float cby = centers[3 * sidx + 1];
    float cbz = centers[3 * sidx + 2];
    float nx = px - cbx, ny = py - cby, nz = pz - cbz;
    float nn  = sqrtf(nx * nx + ny * ny + nz * nz);
    float nin = 1.0f / fmaxf(nn, NRM_EPS);
    nx *= nin; ny *= nin; nz *= nin;

    // direction to sampled light
    int li = light_idx[i];
    float dsx = light_pos[3 * li + 0] - px;
    float dsy = light_pos[3 * li + 1] - py;
    float dsz = light_pos[3 * li + 2] - pz;

    // Duff et al. branchless orthonormal frame; local = (d.s, d.t, d.n)
    float sgn = (nz >= 0.0f) ? 1.0f : -1.0f;
    float a   = -1.0f / (sgn + nz);
    float bb  = nx * ny * a;
    float sx = 1.0f + sgn * nx * nx * a, sy = sgn * bb,          sz = -sgn * nx;
    float tx = bb,                       ty = sgn + ny * ny * a, tz = -ny;

    float l0 = dsx * sx + dsy * sy + dsz * sz;
    float l1 = dsx * tx + dsy * ty + dsz * tz;
    float l2 = dsx * nx + dsy * ny + dsz * nz;
    float ln  = sqrtf(l0 * l0 + l1 * l1 + l2 * l2);
    float lin = 1.0f / fmaxf(ln, NRM_EPS);

    float r0 = active ? (l0 * lin + 1.0f) * 0.5f : 0.0f;
    float r1 = active ? (l1 * lin + 1.0f) * 0.5f : 0.0f;
    float r2 = active ? (l2 * lin + 1.0f) * 0.5f : 0.0f;

    out[3 * i + 0] = (1.0f + r0) * 0.5f;
    out[3 * i + 1] = (1.0f + r1) * 0.5f;
    out[3 * i + 2] = (1.0f + r2) * 0.5f;
    out[(size_t)3 * N + i] = active ? 1.0f : 0.0f;
}

extern "C" void kernel_launch(void* const* d_in, const int* in_sizes, int n_in,
                              void* d_out, int out_size, void* d_ws, size_t ws_size,
                              hipStream_t stream) {
    const float* ray_o     = (const float*)d_in[0];
    const float* ray_d     = (const float*)d_in[1];
    const float* centers   = (const float*)d_in[2];
    const float* radii     = (const float*)d_in[3];
    const float* light_pos = (const float*)d_in[4];
    const int*   light_idx = (const int*)d_in[5];
    float* out = (float*)d_out;
    float* tb  = (float*)d_ws;

    const int N = in_sizes[0] / 3;
    const int S = in_sizes[3];
    const int SP = S >> 1;

    prep_kernel<<<1, 64, 0, stream>>>(centers, (const float*)d_in[3], tb, SP);

    const int block = 256;
    const int grid  = (N + block - 1) / block;
    illum_kernel<<<grid, block, 0, stream>>>(ray_o, ray_d, centers,
                                             light_pos, light_idx, tb, out, N, S);
}

// Round 4
// 37.146 us; speedup vs baseline: 1.0927x; 1.0927x over previous
//
#include <hip/hip_runtime.h>
#include <math.h>

#define EPS_T 1e-4f
#define BIG 1e10f
#define NRM_EPS 1e-12f

constexpr int MAX_SP = 64;   // sphere pairs (S=128)

__global__ __launch_bounds__(256) void illum_kernel(
    const float* __restrict__ ray_o,
    const float* __restrict__ ray_d,
    const float* __restrict__ centers,
    const float* __restrict__ radii,
    const float* __restrict__ light_pos,
    const int*   __restrict__ light_idx,
    float* __restrict__ out,   // [N*3] results, then [N] active(0/1)
    int N, int S)
{
    // pair-SoA: sAB = (x0,x1,y0,y1), sZW = (z0,z1,w0,w1), w = |c|^2 - r^2
    __shared__ float4 sAB[MAX_SP];
    __shared__ float4 sZW[MAX_SP];

    const int tid = threadIdx.x;
    const int SP = S >> 1;
    if (tid < SP) {
        float x0 = centers[6 * tid + 0], y0 = centers[6 * tid + 1], z0 = centers[6 * tid + 2];
        float x1 = centers[6 * tid + 3], y1 = centers[6 * tid + 4], z1 = centers[6 * tid + 5];
        float r0 = radii[2 * tid + 0],   r1 = radii[2 * tid + 1];
        float w0 = x0 * x0 + y0 * y0 + z0 * z0 - r0 * r0;
        float w1 = x1 * x1 + y1 * y1 + z1 * z1 - r1 * r1;
        sAB[tid] = make_float4(x0, x1, y0, y1);
        sZW[tid] = make_float4(z0, z1, w0, w1);
    }
    __syncthreads();

    // two rays per thread: rA = 2*ti, rB = 2*ti+1
    const int ti = blockIdx.x * blockDim.x + tid;
    const int rA = 2 * ti;
    const int rB = rA + 1;
    if (rA >= N) return;
    const bool hasB = (rB < N);

    const float2* o2 = (const float2*)ray_o;
    const float2* d2 = (const float2*)ray_d;
    // rays rA,rB occupy floats [6ti .. 6ti+5] -> three aligned float2 loads each array
    float2 oa = o2[3 * ti + 0], ob = o2[3 * ti + 1], oc = o2[3 * ti + 2];
    float2 da = d2[3 * ti + 0], db = d2[3 * ti + 1], dc = d2[3 * ti + 2];

    float oxA = oa.x, oyA = oa.y, ozA = ob.x;
    float oxB = ob.y, oyB = oc.x, ozB = oc.y;
    float dxA = da.x, dyA = da.y, dzA = db.x;
    float dxB = db.y, dyB = dc.x, dzB = dc.y;

    // normalize directions (precise, once per ray)
    float dnA  = sqrtf(dxA * dxA + dyA * dyA + dzA * dzA);
    float dinA = 1.0f / fmaxf(dnA, NRM_EPS);
    dxA *= dinA; dyA *= dinA; dzA *= dinA;
    float dnB  = sqrtf(dxB * dxB + dyB * dyB + dzB * dzB);
    float dinB = 1.0f / fmaxf(dnB, NRM_EPS);
    dxB *= dinB; dyB *= dinB; dzB *= dinB;

    const float odA = oxA * dxA + oyA * dyA + ozA * dzA;
    const float ooA = oxA * oxA + oyA * oyA + ozA * ozA;
    const float odB = oxB * dxB + oyB * dyB + ozB * dzB;
    const float ooB = oxB * oxB + oyB * oyB + ozB * ozB;

    float tmA = BIG, tmB = BIG;
    int   idA = 0,   idB = 0;

    #pragma unroll 4
    for (int j = 0; j < SP; ++j) {
        float4 ab = sAB[j];
        float4 zw = sZW[j];
        // sphere 0 of pair
        {
            const float cx = ab.x, cy = ab.z, cz = zw.x, cw = zw.z;
            // ray A
            float docA = fmaf(dxA, cx, fmaf(dyA, cy, dzA * cz));
            float oocA = fmaf(oxA, cx, fmaf(oyA, cy, ozA * cz));
            float bmA  = docA - odA;
            float cvA  = fmaf(-2.0f, oocA, ooA) + cw;
            float dscA = fmaf(bmA, bmA, -cvA);
            float tA   = bmA - __builtin_amdgcn_sqrtf(dscA);
            bool cA = (dscA > 0.0f) & (tA > EPS_T) & (tA < tmA);
            tmA = cA ? tA : tmA;  idA = cA ? (2 * j) : idA;
            // ray B (independent chain, same sphere constants)
            float docB = fmaf(dxB, cx, fmaf(dyB, cy, dzB * cz));
            float oocB = fmaf(oxB, cx, fmaf(oyB, cy, ozB * cz));
            float bmB  = docB - odB;
            float cvB  = fmaf(-2.0f, oocB, ooB) + cw;
            float dscB = fmaf(bmB, bmB, -cvB);
            float tB   = bmB - __builtin_amdgcn_sqrtf(dscB);
            bool cB = (dscB > 0.0f) & (tB > EPS_T) & (tB < tmB);
            tmB = cB ? tB : tmB;  idB = cB ? (2 * j) : idB;
        }
        // sphere 1 of pair
        {
            const float cx = ab.y, cy = ab.w, cz = zw.y, cw = zw.w;
            float docA = fmaf(dxA, cx, fmaf(dyA, cy, dzA * cz));
            float oocA = fmaf(oxA, cx, fmaf(oyA, cy, ozA * cz));
            float bmA  = docA - odA;
            float cvA  = fmaf(-2.0f, oocA, ooA) + cw;
            float dscA = fmaf(bmA, bmA, -cvA);
            float tA   = bmA - __builtin_amdgcn_sqrtf(dscA);
            bool cA = (dscA > 0.0f) & (tA > EPS_T) & (tA < tmA);
            tmA = cA ? tA : tmA;  idA = cA ? (2 * j + 1) : idA;
            float docB = fmaf(dxB, cx, fmaf(dyB, cy, dzB * cz));
            float oocB = fmaf(oxB, cx, fmaf(oyB, cy, ozB * cz));
            float bmB  = docB - odB;
            float cvB  = fmaf(-2.0f, oocB, ooB) + cw;
            float dscB = fmaf(bmB, bmB, -cvB);
            float tB   = bmB - __builtin_amdgcn_sqrtf(dscB);
            bool cB = (dscB > 0.0f) & (tB > EPS_T) & (tB < tmB);
            tmB = cB ? tB : tmB;  idB = cB ? (2 * j + 1) : idB;
        }
    }

    // ---- epilogue (once per ray) ----
    auto shade = [&](float ox, float oy, float oz, float dx, float dy, float dz,
                     float tmin, int sidx, int ray, float* res) {
        const bool active = (tmin < BIG);
        float px = fmaf(tmin, dx, ox);
        float py = fmaf(tmin, dy, oy);
        float pz = fmaf(tmin, dz, oz);
        float cbx = centers[3 * sidx + 0];
        float cby = centers[3 * sidx + 1];
        float cbz = centers[3 * sidx + 2];
        float nx = px - cbx, ny = py - cby, nz = pz - cbz;
        float nn  = sqrtf(nx * nx + ny * ny + nz * nz);
        float nin = 1.0f / fmaxf(nn, NRM_EPS);
        nx *= nin; ny *= nin; nz *= nin;
        int li = light_idx[ray];
        float dsx = light_pos[3 * li + 0] - px;
        float dsy = light_pos[3 * li + 1] - py;
        float dsz = light_pos[3 * li + 2] - pz;
        float sgn = (nz >= 0.0f) ? 1.0f : -1.0f;
        float a   = -1.0f / (sgn + nz);
        float bb  = nx * ny * a;
        float sx = 1.0f + sgn * nx * nx * a, sy = sgn * bb,          sz = -sgn * nx;
        float tx = bb,                       ty = sgn + ny * ny * a, tz = -ny;
        float l0 = dsx * sx + dsy * sy + dsz * sz;
        float l1 = dsx * tx + dsy * ty + dsz * tz;
        float l2 = dsx * nx + dsy * ny + dsz * nz;
        float ln  = sqrtf(l0 * l0 + l1 * l1 + l2 * l2);
        float lin = 1.0f / fmaxf(ln, NRM_EPS);
        res[0] = active ? ((l0 * lin + 1.0f) * 0.5f + 1.0f) * 0.5f : 0.5f;
        res[1] = active ? ((l1 * lin + 1.0f) * 0.5f + 1.0f) * 0.5f : 0.5f;
        res[2] = active ? ((l2 * lin + 1.0f) * 0.5f + 1.0f) * 0.5f : 0.5f;
        res[3] = active ? 1.0f : 0.0f;
    };

    float resA[4], resB[4] = {0.5f, 0.5f, 0.5f, 0.0f};
    shade(oxA, oyA, ozA, dxA, dyA, dzA, tmA, idA, rA, resA);
    if (hasB) shade(oxB, oyB, ozB, dxB, dyB, dzB, tmB, idB, rB, resB);

    // results: 6 consecutive floats at out[6*ti], 8B-aligned -> float2 stores
    float2* ro = (float2*)(out + 6 * (size_t)ti);
    ro[0] = make_float2(resA[0], resA[1]);
    if (hasB) {
        ro[1] = make_float2(resA[2], resB[0]);
        ro[2] = make_float2(resB[1], resB[2]);
        float2* ao = (float2*)(out + 3 * (size_t)N + 2 * (size_t)ti);
        ao[0] = make_float2(resA[3], resB[3]);
    } else {
        out[6 * (size_t)ti + 2] = resA[2];
        out[3 * (size_t)N + rA] = resA[3];
    }
}

extern "C" void kernel_launch(void* const* d_in, const int* in_sizes, int n_in,
                              void* d_out, int out_size, void* d_ws, size_t ws_size,
                              hipStream_t stream) {
    const float* ray_o     = (const float*)d_in[0];
    const float* ray_d     = (const float*)d_in[1];
    const float* centers   = (const float*)d_in[2];
    const float* radii     = (const float*)d_in[3];
    const float* light_pos = (const float*)d_in[4];
    const int*   light_idx = (const int*)d_in[5];
    float* out = (float*)d_out;

    const int N = in_sizes[0] / 3;
    const int S = in_sizes[3];

    const int NP = (N + 1) / 2;          // ray pairs, one per thread
    const int block = 256;
    const int grid  = (NP + block - 1) / block;
    illum_kernel<<<grid, block, 0, stream>>>(ray_o, ray_d, centers, radii,
                                             light_pos, light_idx, out, N, S);
}

// Round 6
// 32.145 us; speedup vs baseline: 1.2628x; 1.1556x over previous
//
#include <hip/hip_runtime.h>
#include <math.h>

#define EPS_T 1e-4f
#define BIG 1e10f
#define NRM_EPS 1e-12f

typedef float v2f __attribute__((ext_vector_type(2)));

// ---- inline-asm pair body ----------------------------------------------
// Registers (physical, clobbered):
//   v[32:33] U = d.c (packed over 2 spheres)   v[34:35] V = o.c
//   v[36:37] BM = U - od (= -b)                v[38:39] NCV, then DSC
//   v[40:47] BUF0 (cx2,cy2,cz2,-w2)            v[48:55] BUF1
//   v56,v57  sqrt / t scratch
// Table per pair j: float4 (x0,x1,y0,y1), float4 (z0,z1,-w0,-w1), w=|c|^2-r^2.
// Bit-exact match of the round-4-passed scalar forms:
//   doc = fma(dx,cx, fma(dy,cy, dz*cz));  ooc likewise
//   bm  = doc - od        (as doc + (-od))
//   ncv = fma(ooc,2,-oo) + (-w)   ( == -(fma(-2,ooc,oo) + w) exactly, RNE )
//   dsc = fma(bm, bm, ncv)        ( == fmaf(bm,bm,-cv) exactly )
//   t   = bm - v_sqrt(dsc); dsc<0 -> NaN -> ordered compares false (rejected)
#define PF0 \
  "ds_read_b128 v[40:43], %[lda] offset:0\n\t" \
  "ds_read_b128 v[44:47], %[lda] offset:16\n\t" \
  "v_add_u32 %[lda], 32, %[lda]\n\t"
#define PF1 \
  "ds_read_b128 v[48:51], %[lda] offset:0\n\t" \
  "ds_read_b128 v[52:55], %[lda] offset:16\n\t" \
  "v_add_u32 %[lda], 32, %[lda]\n\t"

#define PBODY(W, CX, CY, CZ, CWN, PF) \
  W \
  "v_pk_mul_f32 v[32:33], %[dz2], " CZ "\n\t" \
  "v_pk_mul_f32 v[34:35], %[oz2], " CZ "\n\t" \
  "v_pk_fma_f32 v[32:33], %[dy2], " CY ", v[32:33]\n\t" \
  "v_pk_fma_f32 v[34:35], %[oy2], " CY ", v[34:35]\n\t" \
  "v_pk_fma_f32 v[32:33], %[dx2], " CX ", v[32:33]\n\t" \
  "v_pk_fma_f32 v[34:35], %[ox2], " CX ", v[34:35]\n\t" \
  "v_pk_add_f32 v[36:37], v[32:33], %[nod2]\n\t" \
  "v_pk_fma_f32 v[38:39], v[34:35], %[two2], %[noo2]\n\t" \
  "v_pk_add_f32 v[38:39], v[38:39], " CWN "\n\t" \
  PF \
  "v_pk_fma_f32 v[38:39], v[36:37], v[36:37], v[38:39]\n\t" \
  "v_sqrt_f32 v56, v38\n\t" \
  "v_sqrt_f32 v57, v39\n\t" \
  "v_sub_f32 v56, v36, v56\n\t" \
  "v_sub_f32 v57, v37, v57\n\t" \
  "v_cmp_lt_f32 vcc, %[eps], v56\n\t" \
  "v_cmp_gt_f32 s[20:21], %[tme], v56\n\t" \
  "s_and_b64 vcc, vcc, s[20:21]\n\t" \
  "v_cndmask_b32 %[tme], %[tme], v56, vcc\n\t" \
  "v_cndmask_b32 %[ide], %[ide], %[vj], vcc\n\t" \
  "v_cmp_lt_f32 vcc, %[eps], v57\n\t" \
  "v_cmp_gt_f32 s[20:21], %[tmo], v57\n\t" \
  "s_and_b64 vcc, vcc, s[20:21]\n\t" \
  "v_cndmask_b32 %[tmo], %[tmo], v57, vcc\n\t" \
  "v_cndmask_b32 %[ido], %[ido], %[vj], vcc\n\t" \
  "v_add_u32 %[vj], 1, %[vj]\n\t"

__global__ __launch_bounds__(256) void illum_kernel(
    const float* __restrict__ ray_o,
    const float* __restrict__ ray_d,
    const float* __restrict__ centers,
    const float* __restrict__ radii,
    const float* __restrict__ light_pos,
    const int*   __restrict__ light_idx,
    float* __restrict__ out,   // [N*3] results, then [N] active(0/1)
    int N)
{
    __shared__ float4 tab[128];   // pair j: tab[2j]=(x0,x1,y0,y1), tab[2j+1]=(z0,z1,-w0,-w1)

    const int tid = threadIdx.x;
    if (tid < 64) {
        float x0 = centers[6 * tid + 0], y0 = centers[6 * tid + 1], z0 = centers[6 * tid + 2];
        float x1 = centers[6 * tid + 3], y1 = centers[6 * tid + 4], z1 = centers[6 * tid + 5];
        float r0 = radii[2 * tid + 0],   r1 = radii[2 * tid + 1];
        float w0 = x0 * x0 + y0 * y0 + z0 * z0 - r0 * r0;
        float w1 = x1 * x1 + y1 * y1 + z1 * z1 - r1 * r1;
        tab[2 * tid + 0] = make_float4(x0, x1, y0, y1);
        tab[2 * tid + 1] = make_float4(z0, z1, -w0, -w1);
    }
    __syncthreads();

    const int i = blockIdx.x * blockDim.x + tid;
    if (i >= N) return;

    float ox = ray_o[3 * i + 0], oy = ray_o[3 * i + 1], oz = ray_o[3 * i + 2];
    float dx = ray_d[3 * i + 0], dy = ray_d[3 * i + 1], dz = ray_d[3 * i + 2];

    // d = normalize(ray_d), precise (once per ray)
    float dn  = sqrtf(dx * dx + dy * dy + dz * dz);
    float din = 1.0f / fmaxf(dn, NRM_EPS);
    dx *= din; dy *= din; dz *= din;

    const float od = ox * dx + oy * dy + oz * dz;
    const float oo = ox * ox + oy * oy + oz * oz;

    v2f dx2 = {dx, dx}, dy2 = {dy, dy}, dz2 = {dz, dz};
    v2f ox2 = {ox, ox}, oy2 = {oy, oy}, oz2 = {oz, oz};
    v2f nod2 = {-od, -od};
    v2f noo2 = {-oo, -oo};
    v2f two2 = {2.0f, 2.0f};

    float tme = BIG, tmo = BIG;
    int ide = 0, ido = 0, vj = 0;
    // generic shared-pointer low 32 bits == LDS byte offset
    unsigned lda = (unsigned)(size_t)&tab[0];

    asm volatile(
        "s_waitcnt lgkmcnt(0)\n\t"
        PF0
        PF1
        ".rept 31\n\t"
        PBODY("s_waitcnt lgkmcnt(2)\n\t", "v[40:41]", "v[42:43]", "v[44:45]", "v[46:47]", PF0)
        PBODY("s_waitcnt lgkmcnt(2)\n\t", "v[48:49]", "v[50:51]", "v[52:53]", "v[54:55]", PF1)
        ".endr\n\t"
        PBODY("s_waitcnt lgkmcnt(2)\n\t", "v[40:41]", "v[42:43]", "v[44:45]", "v[46:47]", "")
        PBODY("s_waitcnt lgkmcnt(0)\n\t", "v[48:49]", "v[50:51]", "v[52:53]", "v[54:55]", "")
        : [tme]"+v"(tme), [tmo]"+v"(tmo), [ide]"+v"(ide), [ido]"+v"(ido),
          [vj]"+v"(vj), [lda]"+v"(lda)
        : [dx2]"v"(dx2), [dy2]"v"(dy2), [dz2]"v"(dz2),
          [ox2]"v"(ox2), [oy2]"v"(oy2), [oz2]"v"(oz2),
          [nod2]"v"(nod2), [noo2]"v"(noo2), [two2]"v"(two2),
          [eps]"s"(1e-4f)
        : "v32","v33","v34","v35","v36","v37","v38","v39",
          "v40","v41","v42","v43","v44","v45","v46","v47",
          "v48","v49","v50","v51","v52","v53","v54","v55","v56","v57",
          "s20","s21","vcc","scc","memory");

    // merge chains: even-sphere winner (idx 2*ide) vs odd (2*ido+1),
    // index-aware tie-break preserves jnp.argmin first-occurrence exactly.
    int iE = 2 * ide, iO = 2 * ido + 1;
    bool ow = (tmo < tme) | ((tmo == tme) & (iO < iE));
    float tmin = ow ? tmo : tme;
    int   sidx = ow ? iO  : iE;

    const bool active = (tmin < BIG);

    // hit point
    float px = fmaf(tmin, dx, ox);
    float py = fmaf(tmin, dy, oy);
    float pz = fmaf(tmin, dz, oz);

    // surface normal (center from LDS table)
    float4 ab = tab[2 * (sidx >> 1) + 0];
    float4 zw = tab[2 * (sidx >> 1) + 1];
    float cbx = (sidx & 1) ? ab.y : ab.x;
    float cby = (sidx & 1) ? ab.w : ab.z;
    float cbz = (sidx & 1) ? zw.y : zw.x;
    float nx = px - cbx, ny = py - cby, nz = pz - cbz;
    float nn  = sqrtf(nx * nx + ny * ny + nz * nz);
    float nin = 1.0f / fmaxf(nn, NRM_EPS);
    nx *= nin; ny *= nin; nz *= nin;

    // direction to sampled light
    int li = light_idx[i];
    float dsx = light_pos[3 * li + 0] - px;
    float dsy = light_pos[3 * li + 1] - py;
    float dsz = light_pos[3 * li + 2] - pz;

    // Duff et al. branchless orthonormal frame; local = (d.s, d.t, d.n)
    float sgn = (nz >= 0.0f) ? 1.0f : -1.0f;
    float a   = -1.0f / (sgn + nz);
    float bb  = nx * ny * a;
    float sx = 1.0f + sgn * nx * nx * a, sy = sgn * bb,          sz = -sgn * nx;
    float tx = bb,                       ty = sgn + ny * ny * a, tz = -ny;

    float l0 = dsx * sx + dsy * sy + dsz * sz;
    float l1 = dsx * tx + dsy * ty + dsz * tz;
    float l2 = dsx * nx + dsy * ny + dsz * nz;
    float ln  = sqrtf(l0 * l0 + l1 * l1 + l2 * l2);
    float lin = 1.0f / fmaxf(ln, NRM_EPS);

    float r0 = active ? (l0 * lin + 1.0f) * 0.5f : 0.0f;
    float r1 = active ? (l1 * lin + 1.0f) * 0.5f : 0.0f;
    float r2 = active ? (l2 * lin + 1.0f) * 0.5f : 0.0f;

    out[3 * i + 0] = (1.0f + r0) * 0.5f;
    out[3 * i + 1] = (1.0f + r1) * 0.5f;
    out[3 * i + 2] = (1.0f + r2) * 0.5f;
    out[(size_t)3 * N + i] = active ? 1.0f : 0.0f;
}

extern "C" void kernel_launch(void* const* d_in, const int* in_sizes, int n_in,
                              void* d_out, int out_size, void* d_ws, size_t ws_size,
                              hipStream_t stream) {
    const float* ray_o     = (const float*)d_in[0];
    const float* ray_d     = (const float*)d_in[1];
    const float* centers   = (const float*)d_in[2];
    const float* radii     = (const float*)d_in[3];
    const float* light_pos = (const float*)d_in[4];
    const int*   light_idx = (const int*)d_in[5];
    float* out = (float*)d_out;

    const int N = in_sizes[0] / 3;   // S is fixed at 128 for this problem

    const int block = 256;
    const int grid  = (N + block - 1) / block;
    illum_kernel<<<grid, block, 0, stream>>>(ray_o, ray_d, centers, radii,
                                             light_pos, light_idx, out, N);
}